// Round 2
// baseline (399.036 us; speedup 1.0000x reference)
//
#include <hip/hip_runtime.h>
#include <hip/hip_bf16.h>

// Joint network: out[b,t,u,o] = tanh(enc_proj[b,t,:] + dec_proj[b,u,:] + b1) @ W2 + b2
// B=8 T=256 U=64 D=512 H=1024 O=128.  All I/O fp32 (per reference dtypes).
//
// ws layout (bf16 internals):
//   W1T bf16 [1024][1024]  @ 0         (2 MiB)   W1T[h][d] = W1[d][h]
//   W2T bf16 [128][1024]   @ 2 MiB     (256 KiB) W2T[o][h] = W2[h][o]
//   ep  bf16 [2048][1024]  @ 2.25 MiB  (4 MiB)   ep = C2L*(enc@W1[:512] + b1)
//   dp  bf16 [512][1024]   @ 6.25 MiB  (1 MiB)   dp = C2L*(dec@W1[512:])
// C2L = 2*log2(e) prescale so tanh(x) = 1 - 2*rcp(exp2(ep+dp)+1).

typedef short  bf16x8 __attribute__((ext_vector_type(8)));
typedef float  f32x4  __attribute__((ext_vector_type(4)));

#define C2L 2.8853900817779268f

__device__ __forceinline__ unsigned short f2bf(float f) {
    union { float f; unsigned int u; } c; c.f = f;
    unsigned int u = c.u + 0x7FFFu + ((c.u >> 16) & 1u);
    return (unsigned short)(u >> 16);
}
__device__ __forceinline__ unsigned int pack2(float x, float y) {
    __hip_bfloat162 h = __float22bfloat162_rn(float2{x, y});
    union { __hip_bfloat162 h; unsigned int u; } c; c.h = h; return c.u;
}
__device__ __forceinline__ float bf2f(unsigned short h) {
    union { unsigned int u; float f; } c; c.u = ((unsigned int)h) << 16; return c.f;
}
__device__ __forceinline__ float fast_exp2(float x) { return __builtin_amdgcn_exp2f(x); }
__device__ __forceinline__ float fast_rcp(float x)  { return __builtin_amdgcn_rcpf(x); }

// ---------------------------------------------------------------- transpose
// dst(bf16)[C][R] <- src(fp32)[R][C], R,C multiples of 32
__global__ __launch_bounds__(1024) void transpose_w(
    const float* __restrict__ src, unsigned short* __restrict__ dst,
    int R, int C)
{
    __shared__ float tile[32][33];
    int c0 = blockIdx.x * 32, r0 = blockIdx.y * 32;
    int tx = threadIdx.x, ty = threadIdx.y;
    tile[ty][tx] = src[(r0 + ty) * C + (c0 + tx)];
    __syncthreads();
    dst[(c0 + ty) * R + (r0 + tx)] = f2bf(tile[tx][ty]);
}

// ---------------------------------------------------------------- projection
// P(bf16)[M][1024] = C2L * (A(fp32)[M][512] @ W1[koff:koff+512][:] + bias?)
// W1T bf16 [1024][1024] (h-major, d-contiguous)
__global__ __launch_bounds__(256) void gemm_proj(
    const float* __restrict__ A,
    const unsigned short* __restrict__ W1T,
    const float* __restrict__ bias,   // b1 or nullptr
    unsigned short* __restrict__ P,
    int koff)
{
    const int K = 512;
    int tid  = threadIdx.x;
    int w    = tid >> 6, lane = tid & 63;
    int quad = lane >> 4, l15 = lane & 15;
    int m_base = blockIdx.y * 64 + w * 16;
    int n_base = blockIdx.x * 64;

    f32x4 acc[4] = {};
    const float* a_row = A + (size_t)(m_base + l15) * K;

    for (int kc = 0; kc < K; kc += 32) {
        int k = kc + quad * 8;
        float4 a_lo = *reinterpret_cast<const float4*>(a_row + k);
        float4 a_hi = *reinterpret_cast<const float4*>(a_row + k + 4);
        union { bf16x8 v; unsigned int u[4]; } a;
        a.u[0] = pack2(a_lo.x, a_lo.y);
        a.u[1] = pack2(a_lo.z, a_lo.w);
        a.u[2] = pack2(a_hi.x, a_hi.y);
        a.u[3] = pack2(a_hi.z, a_hi.w);
        #pragma unroll
        for (int f = 0; f < 4; ++f) {
            int n = n_base + f * 16 + l15;
            bf16x8 b = *reinterpret_cast<const bf16x8*>(W1T + n * 1024 + koff + k);
            acc[f] = __builtin_amdgcn_mfma_f32_16x16x32_bf16(a.v, b, acc[f], 0, 0, 0);
        }
    }

    #pragma unroll
    for (int f = 0; f < 4; ++f) {
        int col = n_base + f * 16 + l15;
        float bv = bias ? bias[col] : 0.0f;
        #pragma unroll
        for (int v = 0; v < 4; ++v) {
            int row = m_base + quad * 4 + v;
            P[row * 1024 + col] = f2bf(C2L * (acc[f][v] + bv));
        }
    }
}

// ---------------------------------------------------------------- main fused
// One block per (b,t): 64 u-rows x 128 o-cols. 4 waves, each 16 rows x 128 cols.
__global__ __launch_bounds__(256) void joint_main(
    const unsigned short* __restrict__ ep,    // [2048][1024] bf16
    const unsigned short* __restrict__ dp,    // [512][1024]  bf16
    const unsigned short* __restrict__ W2T,   // [128][1024]  bf16
    const float* __restrict__ b2,             // [128] fp32
    float* __restrict__ out)                  // [8][256][64][128] fp32
{
    int t = blockIdx.x, b = blockIdx.y;
    int tid  = threadIdx.x;
    int w    = tid >> 6, lane = tid & 63;
    int quad = lane >> 4, l15 = lane & 15;
    int u0   = w * 16;

    const unsigned short* ep_row = ep + (b * 256 + t) * 1024;
    const unsigned short* dp_row = dp + (b * 64 + u0 + l15) * 1024;

    f32x4 acc[8] = {};
    float b2f[8];
    #pragma unroll
    for (int f = 0; f < 8; ++f) b2f[f] = b2[f * 16 + l15];

    for (int kc = 0; kc < 1024; kc += 32) {
        int k = kc + quad * 8;
        bf16x8 e8 = *reinterpret_cast<const bf16x8*>(ep_row + k);
        bf16x8 d8 = *reinterpret_cast<const bf16x8*>(dp_row + k);

        union { bf16x8 v; unsigned int u[4]; } a;
        #pragma unroll
        for (int jj = 0; jj < 4; ++jj) {
            float x0 = bf2f((unsigned short)e8[2*jj])   + bf2f((unsigned short)d8[2*jj]);
            float x1 = bf2f((unsigned short)e8[2*jj+1]) + bf2f((unsigned short)d8[2*jj+1]);
            // tanh(x) = 1 - 2/(exp2(C2L*x)+1); argument already prescaled by C2L
            float h0 = 1.0f - 2.0f * fast_rcp(fast_exp2(x0) + 1.0f);
            float h1 = 1.0f - 2.0f * fast_rcp(fast_exp2(x1) + 1.0f);
            a.u[jj] = pack2(h0, h1);
        }

        #pragma unroll
        for (int f = 0; f < 8; ++f) {
            bf16x8 bb = *reinterpret_cast<const bf16x8*>(W2T + (f * 16 + l15) * 1024 + k);
            acc[f] = __builtin_amdgcn_mfma_f32_16x16x32_bf16(a.v, bb, acc[f], 0, 0, 0);
        }
    }

    float* outp = out + (size_t)(b * 256 + t) * 64 * 128;
    #pragma unroll
    for (int f = 0; f < 8; ++f) {
        int o = f * 16 + l15;
        #pragma unroll
        for (int v = 0; v < 4; ++v) {
            int u = u0 + quad * 4 + v;
            outp[u * 128 + o] = acc[f][v] + b2f[f];
        }
    }
}

// ---------------------------------------------------------------- launch
extern "C" void kernel_launch(void* const* d_in, const int* in_sizes, int n_in,
                              void* d_out, int out_size, void* d_ws, size_t ws_size,
                              hipStream_t stream) {
    const float* enc = (const float*)d_in[0]; // [8][256][512]
    const float* dec = (const float*)d_in[1]; // [8][64][512]
    const float* W1  = (const float*)d_in[2]; // [1024][1024]
    const float* b1  = (const float*)d_in[3]; // [1024]
    const float* W2  = (const float*)d_in[4]; // [1024][128]
    const float* b2  = (const float*)d_in[5]; // [128]
    float* out = (float*)d_out;

    char* ws = (char*)d_ws;
    unsigned short* W1T = (unsigned short*)(ws);                               // 2 MiB
    unsigned short* W2T = (unsigned short*)(ws + (2u << 20));                  // 256 KiB
    unsigned short* ep  = (unsigned short*)(ws + (2u << 20) + (256u << 10));   // 4 MiB
    unsigned short* dp  = (unsigned short*)(ws + (6u << 20) + (256u << 10));   // 1 MiB

    dim3 tb(32, 32);
    transpose_w<<<dim3(32, 32), tb, 0, stream>>>(W1, W1T, 1024, 1024);
    transpose_w<<<dim3(4, 32),  tb, 0, stream>>>(W2, W2T, 1024, 128);

    // ep = C2L*(enc @ W1[:512] + b1): M=2048
    gemm_proj<<<dim3(16, 32), 256, 0, stream>>>(enc, W1T, b1, ep, 0);
    // dp = C2L*(dec @ W1[512:]): M=512
    gemm_proj<<<dim3(16, 8),  256, 0, stream>>>(dec, W1T, nullptr, dp, 512);

    joint_main<<<dim3(256, 8), 256, 0, stream>>>(ep, dp, W2T, b2, out);
}

// Round 5
// 209.425 us; speedup vs baseline: 1.9054x; 1.9054x over previous
//
#include <hip/hip_runtime.h>
#include <hip/hip_bf16.h>

// Joint network: out[b,t,u,o] = tanh(enc_proj[b,t,:] + dec_proj[b,u,:] + b1) @ W2 + b2
// B=8 T=256 U=64 D=512 H=1024 O=128.  All I/O fp32.
//
// Key identity: with C2L = 2*log2(e),
//   tanh(x) = 1 - 2/(2^(C2L*x) + 1)
//   2^(C2L*(e+d+b1)) = Ep * Dp  where Ep=2^(C2L*(e+b1)), Dp=2^(C2L*d)
// Ep/Dp precomputed in the projection epilogue, stored fp16.
//
// ws layout (f16 internals):
//   W1T f16 [1024][1024]  @ 0       (2 MiB)    W1T[h][d] = W1[d][h]
//   W2T f16 [128][1024]   @ 2 MiB   (256 KiB)  W2T[o][h] = W2[h][o]
//   Ep  f16 [2048][1024]  @ 2.25 MiB (4 MiB)
//   Dp  f16 [512][1024]   @ 6.25 MiB (1 MiB)

typedef _Float16 f16x8 __attribute__((ext_vector_type(8)));
typedef _Float16 f16x2 __attribute__((ext_vector_type(2)));
typedef float    f32x4 __attribute__((ext_vector_type(4)));

#define C2L 2.8853900817779268f

__device__ __forceinline__ float fast_exp2(float x) { return __builtin_amdgcn_exp2f(x); }
__device__ __forceinline__ float fast_rcp(float x)  { return __builtin_amdgcn_rcpf(x); }

// v_cvt_pkrtz_f16_f32 returns __fp16x2 — bitcast to our _Float16x2
__device__ __forceinline__ f16x2 pk_cvt(float x, float y) {
    auto r = __builtin_amdgcn_cvt_pkrtz(x, y);
    union { decltype(r) a; f16x2 b; } c; c.a = r; return c.b;
}

// tanh on 8 packed f16: A = 1 - 2*rcp(Ep*Dp + 1)
__device__ __forceinline__ f16x8 tanh8(f16x8 e, f16x8 d) {
    union { f16x8 v; f16x2 h[4]; } t, r;
    t.v = e * d;                       // 4x v_pk_mul_f16
    #pragma unroll
    for (int i = 0; i < 4; ++i) {
        float x0 = (float)t.h[i].x, x1 = (float)t.h[i].y;
        float h0 = 1.0f - 2.0f * fast_rcp(x0 + 1.0f);
        float h1 = 1.0f - 2.0f * fast_rcp(x1 + 1.0f);
        r.h[i] = pk_cvt(h0, h1);
    }
    return r.v;
}

// ---------------------------------------------------------------- transpose
// dst(f16)[C][R] <- src(fp32)[R][C], R,C multiples of 32
__global__ __launch_bounds__(1024) void transpose_w(
    const float* __restrict__ src, _Float16* __restrict__ dst, int R, int C)
{
    __shared__ float tile[32][33];
    int c0 = blockIdx.x * 32, r0 = blockIdx.y * 32;
    int tx = threadIdx.x, ty = threadIdx.y;
    tile[ty][tx] = src[(r0 + ty) * C + (c0 + tx)];
    __syncthreads();
    dst[(c0 + ty) * R + (r0 + tx)] = (_Float16)tile[tx][ty];
}

// ---------------------------------------------------------------- projections
// Fused: rows 0..2047 -> Ep = 2^(C2L*(enc@W1[:512] + b1))
//        rows 2048..2559 -> Dp = 2^(C2L*(dec@W1[512:]))
__global__ __launch_bounds__(256) void proj_exp(
    const float* __restrict__ enc,     // [2048][512]
    const float* __restrict__ dec,     // [512][512]
    const _Float16* __restrict__ W1T,  // [1024][1024]
    const float* __restrict__ b1,      // [1024]
    _Float16* __restrict__ Ep,         // [2048][1024]
    _Float16* __restrict__ Dp)         // [512][1024]
{
    const int K = 512;
    int tid  = threadIdx.x;
    int w    = tid >> 6, lane = tid & 63;
    int quad = lane >> 4, l15 = lane & 15;
    int m_base = blockIdx.y * 64 + w * 16;
    int n_base = blockIdx.x * 64;

    bool is_enc = (m_base < 2048);
    const float* A = is_enc ? (enc + (size_t)(m_base + l15) * K)
                            : (dec + (size_t)(m_base - 2048 + l15) * K);
    int koff = is_enc ? 0 : 512;

    f32x4 acc[4] = {};
    for (int kc = 0; kc < K; kc += 32) {
        int k = kc + quad * 8;
        float4 a_lo = *reinterpret_cast<const float4*>(A + k);
        float4 a_hi = *reinterpret_cast<const float4*>(A + k + 4);
        union { f16x8 v; f16x2 h[4]; } a;
        a.h[0] = pk_cvt(a_lo.x, a_lo.y);
        a.h[1] = pk_cvt(a_lo.z, a_lo.w);
        a.h[2] = pk_cvt(a_hi.x, a_hi.y);
        a.h[3] = pk_cvt(a_hi.z, a_hi.w);
        #pragma unroll
        for (int f = 0; f < 4; ++f) {
            int n = n_base + f * 16 + l15;
            f16x8 b = *reinterpret_cast<const f16x8*>(W1T + n * 1024 + koff + k);
            acc[f] = __builtin_amdgcn_mfma_f32_16x16x32_f16(a.v, b, acc[f], 0, 0, 0);
        }
    }

    #pragma unroll
    for (int f = 0; f < 4; ++f) {
        int col = n_base + f * 16 + l15;
        float bv = is_enc ? b1[col] : 0.0f;
        #pragma unroll
        for (int v = 0; v < 4; ++v) {
            int row = m_base + quad * 4 + v;
            float val = fast_exp2(C2L * (acc[f][v] + bv));
            if (is_enc) Ep[(size_t)row * 1024 + col] = (_Float16)val;
            else        Dp[(size_t)(row - 2048) * 1024 + col] = (_Float16)val;
        }
    }
}

// ---------------------------------------------------------------- main fused
// Block = (b, t-pair): 2 t-values x 64 u-rows x 128 o-cols. 4 waves; wave w owns
// u-rows [16w,16w+16) for BOTH t (shared Dp rows). W2 staged in LDS, BK=128.
#define BK   128
#define LDSK (BK + 8)   // +8 f16 pad -> <=2-way LDS bank aliasing (free)
__global__ __launch_bounds__(256, 3) void joint_main(
    const _Float16* __restrict__ Ep,   // [2048][1024]
    const _Float16* __restrict__ Dp,   // [512][1024]
    const _Float16* __restrict__ W2T,  // [128][1024]
    const float* __restrict__ b2,      // [128]
    float* __restrict__ out)           // [8][256][64][128]
{
    __shared__ _Float16 sB[128][LDSK];

    int t0 = blockIdx.x * 2, b = blockIdx.y;
    int tid  = threadIdx.x;
    int w    = tid >> 6, lane = tid & 63;
    int quad = lane >> 4, l15 = lane & 15;
    int u0   = w * 16;

    const _Float16* ep0 = Ep + (size_t)(b * 256 + t0) * 1024;
    const _Float16* ep1 = ep0 + 1024;
    const _Float16* dpr = Dp + (size_t)(b * 64 + u0 + l15) * 1024;

    float b2v[8];
    #pragma unroll
    for (int f = 0; f < 8; ++f) b2v[f] = b2[f * 16 + l15];

    f32x4 acc0[8] = {}, acc1[8] = {};

    for (int kb = 0; kb < 1024; kb += BK) {
        __syncthreads();
        // stage W2T[0:128][kb:kb+128] -> sB: 128 rows x 16 chunks = 2048 x 16B,
        // 8 chunks per thread
        #pragma unroll
        for (int i = 0; i < 8; ++i) {
            int c   = i * 256 + tid;
            int row = c >> 4, off = (c & 15) * 8;
            *reinterpret_cast<f16x8*>(&sB[row][off]) =
                *reinterpret_cast<const f16x8*>(W2T + row * 1024 + kb + off);
        }
        __syncthreads();

        #pragma unroll
        for (int ki = 0; ki < BK; ki += 32) {
            int k  = kb + ki + quad * 8;
            int kl = ki + quad * 8;
            f16x8 d8 = *reinterpret_cast<const f16x8*>(dpr + k);
            f16x8 e0 = *reinterpret_cast<const f16x8*>(ep0 + k);
            f16x8 e1 = *reinterpret_cast<const f16x8*>(ep1 + k);
            f16x8 A0 = tanh8(e0, d8);
            f16x8 A1 = tanh8(e1, d8);
            #pragma unroll
            for (int f = 0; f < 8; ++f) {
                f16x8 bb = *reinterpret_cast<const f16x8*>(&sB[f * 16 + l15][kl]);
                acc0[f] = __builtin_amdgcn_mfma_f32_16x16x32_f16(A0, bb, acc0[f], 0, 0, 0);
                acc1[f] = __builtin_amdgcn_mfma_f32_16x16x32_f16(A1, bb, acc1[f], 0, 0, 0);
            }
        }
    }

    float* o0 = out + (size_t)(b * 256 + t0) * 64 * 128;
    float* o1 = o0 + 64 * 128;
    #pragma unroll
    for (int f = 0; f < 8; ++f) {
        int o = f * 16 + l15;
        #pragma unroll
        for (int v = 0; v < 4; ++v) {
            int u = u0 + quad * 4 + v;
            o0[u * 128 + o] = acc0[f][v] + b2v[f];
            o1[u * 128 + o] = acc1[f][v] + b2v[f];
        }
    }
}

// ---------------------------------------------------------------- launch
extern "C" void kernel_launch(void* const* d_in, const int* in_sizes, int n_in,
                              void* d_out, int out_size, void* d_ws, size_t ws_size,
                              hipStream_t stream) {
    const float* enc = (const float*)d_in[0]; // [8][256][512]
    const float* dec = (const float*)d_in[1]; // [8][64][512]
    const float* W1  = (const float*)d_in[2]; // [1024][1024]
    const float* b1  = (const float*)d_in[3]; // [1024]
    const float* W2  = (const float*)d_in[4]; // [1024][128]
    const float* b2  = (const float*)d_in[5]; // [128]
    float* out = (float*)d_out;

    char* ws = (char*)d_ws;
    _Float16* W1T = (_Float16*)(ws);                               // 2 MiB
    _Float16* W2T = (_Float16*)(ws + (2u << 20));                  // 256 KiB
    _Float16* EpP = (_Float16*)(ws + (2u << 20) + (256u << 10));   // 4 MiB
    _Float16* DpP = (_Float16*)(ws + (6u << 20) + (256u << 10));   // 1 MiB

    dim3 tb(32, 32);
    transpose_w<<<dim3(32, 32), tb, 0, stream>>>(W1, W1T, 1024, 1024);
    transpose_w<<<dim3(4, 32),  tb, 0, stream>>>(W2, W2T, 1024, 128);

    // fused projections + exp2 epilogue: M = 2048 (enc) + 512 (dec) = 2560
    proj_exp<<<dim3(16, 40), 256, 0, stream>>>(enc, dec, W1T, b1, EpP, DpP);

    joint_main<<<dim3(128, 8), 256, 0, stream>>>(EpP, DpP, W2T, b2, out);
}

// Round 6
// 180.823 us; speedup vs baseline: 2.2068x; 1.1582x over previous
//
#include <hip/hip_runtime.h>
#include <hip/hip_bf16.h>

// Joint network: out[b,t,u,o] = tanh(enc_proj[b,t,:] + dec_proj[b,u,:] + b1) @ W2 + b2
// B=8 T=256 U=64 D=512 H=1024 O=128.  All I/O fp32.
//
// tanh identity: with C2L = 2*log2(e),
//   tanh(x) = 1 - 2/(2^(C2L*x) + 1),  2^(C2L*(e+d+b1)) = Ep * Dp
// Ep/Dp precomputed fp16 in projection epilogue; main loop is pure f16 VALU:
//   x = pk_fma(Ep, Dp, 1); r = v_rcp_f16(x); A = pk_fma(-2, r, 1)
//
// ws: W1T f16 [1024][1024] @0 (2MiB) | W2T f16 [128][1024] @2MiB (256KiB)
//     Ep f16 [2048][1024] @2.25MiB (4MiB) | Dp f16 [512][1024] @6.25MiB (1MiB)

typedef _Float16 f16x8 __attribute__((ext_vector_type(8)));
typedef _Float16 f16x2 __attribute__((ext_vector_type(2)));
typedef float    f32x4 __attribute__((ext_vector_type(4)));

#define C2L 2.8853900817779268f

__device__ __forceinline__ float fast_exp2(float x) { return __builtin_amdgcn_exp2f(x); }

// v_cvt_pkrtz_f16_f32 returns __fp16x2 — bitcast to our _Float16x2
__device__ __forceinline__ f16x2 pk_cvt(float x, float y) {
    auto r = __builtin_amdgcn_cvt_pkrtz(x, y);
    union { decltype(r) a; f16x2 b; } c; c.a = r; return c.b;
}

// all-f16 tanh on 8 packed: A = 1 - 2*rcp(Ep*Dp + 1)
__device__ __forceinline__ f16x8 tanh8(f16x8 e, f16x8 d) {
    const f16x8 one = {1,1,1,1,1,1,1,1};
    const f16x8 two = {2,2,2,2,2,2,2,2};
    union { f16x8 v; _Float16 s[8]; } p, r;
    p.v = e * d + one;                         // v_pk_fma_f16 x4
    #pragma unroll
    for (int i = 0; i < 8; ++i) r.s[i] = __builtin_amdgcn_rcph(p.s[i]);
    return one - two * r.v;                    // v_pk_fma_f16 x4
}

// async 16B global -> LDS (LDS dest is wave-uniform base + lane*16)
__device__ __forceinline__ void stage16(const void* g, void* l) {
    __builtin_amdgcn_global_load_lds(
        (const __attribute__((address_space(1))) unsigned int*)g,
        (__attribute__((address_space(3))) unsigned int*)l, 16, 0, 0);
}

// ---------------------------------------------------------------- transpose
// bx<32: W1 (1024x1024) -> W1T ; bx>=32: W2 (1024x128) -> W2T
__global__ __launch_bounds__(1024) void transpose_both(
    const float* __restrict__ W1, const float* __restrict__ W2,
    _Float16* __restrict__ W1T, _Float16* __restrict__ W2T)
{
    __shared__ float tile[32][33];
    int bx = blockIdx.x;
    const float* src; _Float16* dst; int C, c0;
    if (bx < 32) { src = W1; dst = W1T; C = 1024; c0 = bx * 32; }
    else         { src = W2; dst = W2T; C = 128;  c0 = (bx - 32) * 32; }
    int r0 = blockIdx.y * 32;
    int tx = threadIdx.x, ty = threadIdx.y;
    tile[ty][tx] = src[(r0 + ty) * C + (c0 + tx)];
    __syncthreads();
    dst[(size_t)(c0 + ty) * 1024 + (r0 + tx)] = (_Float16)tile[tx][ty];
}

// ---------------------------------------------------------------- projections
// rows 0..2047 -> Ep = 2^(C2L*(enc@W1[:512] + b1)); rows 2048.. -> Dp (dec, no bias)
__global__ __launch_bounds__(256) void proj_exp(
    const float* __restrict__ enc,     // [2048][512]
    const float* __restrict__ dec,     // [512][512]
    const _Float16* __restrict__ W1T,  // [1024][1024]
    const float* __restrict__ b1,      // [1024]
    _Float16* __restrict__ Ep,         // [2048][1024]
    _Float16* __restrict__ Dp)         // [512][1024]
{
    const int K = 512;
    int tid  = threadIdx.x;
    int w    = tid >> 6, lane = tid & 63;
    int quad = lane >> 4, l15 = lane & 15;
    int m_base = blockIdx.y * 64 + w * 16;
    int n_base = blockIdx.x * 64;

    bool is_enc = (m_base < 2048);
    const float* A = is_enc ? (enc + (size_t)(m_base + l15) * K)
                            : (dec + (size_t)(m_base - 2048 + l15) * K);
    int koff = is_enc ? 0 : 512;

    f32x4 acc[4] = {};
    for (int kc = 0; kc < K; kc += 32) {
        int k = kc + quad * 8;
        float4 a_lo = *reinterpret_cast<const float4*>(A + k);
        float4 a_hi = *reinterpret_cast<const float4*>(A + k + 4);
        union { f16x8 v; f16x2 h[4]; } a;
        a.h[0] = pk_cvt(a_lo.x, a_lo.y);
        a.h[1] = pk_cvt(a_lo.z, a_lo.w);
        a.h[2] = pk_cvt(a_hi.x, a_hi.y);
        a.h[3] = pk_cvt(a_hi.z, a_hi.w);
        #pragma unroll
        for (int f = 0; f < 4; ++f) {
            int n = n_base + f * 16 + l15;
            f16x8 b = *reinterpret_cast<const f16x8*>(W1T + n * 1024 + koff + k);
            acc[f] = __builtin_amdgcn_mfma_f32_16x16x32_f16(a.v, b, acc[f], 0, 0, 0);
        }
    }

    #pragma unroll
    for (int f = 0; f < 4; ++f) {
        int col = n_base + f * 16 + l15;
        float bv = is_enc ? b1[col] : 0.0f;
        #pragma unroll
        for (int v = 0; v < 4; ++v) {
            int row = m_base + quad * 4 + v;
            float val = fast_exp2(C2L * (acc[f][v] + bv));
            if (is_enc) Ep[(size_t)row * 1024 + col] = (_Float16)val;
            else        Dp[(size_t)(row - 2048) * 1024 + col] = (_Float16)val;
        }
    }
}

// ---------------------------------------------------------------- main fused
// Block = (b, t-pair): 2 t x 64 u x 128 o. 4 waves; wave w owns u-rows
// [16w,16w+16) for both t. W2 tile (128x128) staged in LDS via global_load_lds
// with XOR k-chunk swizzle (lane-linear LDS dest; reads land 2 lanes/bank).
__global__ __launch_bounds__(256, 4) void joint_main(
    const _Float16* __restrict__ Ep,   // [2048][1024]
    const _Float16* __restrict__ Dp,   // [512][1024]
    const _Float16* __restrict__ W2T,  // [128][1024]
    const float* __restrict__ b2,      // [128]
    float* __restrict__ out)           // [8][256][64][128]
{
    __shared__ _Float16 sB[128][128];  // sB[o][kc^ (o&15) chunks], 32 KiB
    _Float16* sLin = &sB[0][0];

    int t0 = blockIdx.x * 2, b = blockIdx.y;
    int tid  = threadIdx.x;
    int w    = tid >> 6, lane = tid & 63;
    int quad = lane >> 4, l15 = lane & 15;
    int u0   = w * 16;

    const _Float16* ep0 = Ep + (size_t)(b * 256 + t0) * 1024;
    const _Float16* ep1 = ep0 + 1024;
    const _Float16* dpr = Dp + (size_t)(b * 64 + u0 + l15) * 1024;

    f32x4 acc0[8] = {}, acc1[8] = {};

    for (int kb = 0; kb < 1024; kb += 128) {
        __syncthreads();   // previous tile fully consumed
        // stage W2T[0:128][kb:kb+128]: 2048 x 16B chunks, 8/thread, async
        #pragma unroll
        for (int i = 0; i < 8; ++i) {
            int c   = i * 256 + tid;
            int row = c >> 4, kcs = c & 15;
            const _Float16* g = W2T + row * 1024 + kb + ((kcs ^ (row & 15)) << 3);
            stage16(g, sLin + ((i * 256 + (tid & 0xC0)) << 3));
        }
        __syncthreads();   // vmcnt drain + barrier

        #pragma unroll
        for (int ki = 0; ki < 128; ki += 32) {
            int k  = kb + ki + quad * 8;
            f16x8 d8 = *reinterpret_cast<const f16x8*>(dpr + k);
            f16x8 e0 = *reinterpret_cast<const f16x8*>(ep0 + k);
            f16x8 e1 = *reinterpret_cast<const f16x8*>(ep1 + k);
            f16x8 A0 = tanh8(e0, d8);
            f16x8 A1 = tanh8(e1, d8);
            int kc = (ki >> 3) + quad;
            #pragma unroll
            for (int f = 0; f < 8; ++f) {
                f16x8 bb = *reinterpret_cast<const f16x8*>(
                    &sB[f * 16 + l15][(kc ^ l15) << 3]);
                acc0[f] = __builtin_amdgcn_mfma_f32_16x16x32_f16(A0, bb, acc0[f], 0, 0, 0);
                acc1[f] = __builtin_amdgcn_mfma_f32_16x16x32_f16(A1, bb, acc1[f], 0, 0, 0);
            }
        }
    }

    float* o0 = out + (size_t)(b * 256 + t0) * 64 * 128;
    float* o1 = o0 + 64 * 128;
    #pragma unroll
    for (int f = 0; f < 8; ++f) {
        int o = f * 16 + l15;
        float bv = b2[o];
        #pragma unroll
        for (int v = 0; v < 4; ++v) {
            int u = u0 + quad * 4 + v;
            o0[u * 128 + o] = acc0[f][v] + bv;
            o1[u * 128 + o] = acc1[f][v] + bv;
        }
    }
}

// ---------------------------------------------------------------- launch
extern "C" void kernel_launch(void* const* d_in, const int* in_sizes, int n_in,
                              void* d_out, int out_size, void* d_ws, size_t ws_size,
                              hipStream_t stream) {
    const float* enc = (const float*)d_in[0]; // [8][256][512]
    const float* dec = (const float*)d_in[1]; // [8][64][512]
    const float* W1  = (const float*)d_in[2]; // [1024][1024]
    const float* b1  = (const float*)d_in[3]; // [1024]
    const float* W2  = (const float*)d_in[4]; // [1024][128]
    const float* b2  = (const float*)d_in[5]; // [128]
    float* out = (float*)d_out;

    char* ws = (char*)d_ws;
    _Float16* W1T = (_Float16*)(ws);                               // 2 MiB
    _Float16* W2T = (_Float16*)(ws + (2u << 20));                  // 256 KiB
    _Float16* EpP = (_Float16*)(ws + (2u << 20) + (256u << 10));   // 4 MiB
    _Float16* DpP = (_Float16*)(ws + (6u << 20) + (256u << 10));   // 1 MiB

    transpose_both<<<dim3(36, 32), dim3(32, 32), 0, stream>>>(W1, W2, W1T, W2T);

    // fused projections + exp2 epilogue: M = 2048 (enc) + 512 (dec)
    proj_exp<<<dim3(16, 40), 256, 0, stream>>>(enc, dec, W1T, b1, EpP, DpP);

    joint_main<<<dim3(128, 8), 256, 0, stream>>>(EpP, DpP, W2T, b2, out);
}

// Round 7
// 160.383 us; speedup vs baseline: 2.4880x; 1.1274x over previous
//
#include <hip/hip_runtime.h>
#include <hip/hip_bf16.h>

// Joint network: out[b,t,u,o] = tanh(enc_proj[b,t,:] + dec_proj[b,u,:] + b1) @ W2 + b2
// B=8 T=256 U=64 D=512 H=1024 O=128.  All I/O fp32.
//
// tanh identity: with C2L = 2*log2(e),
//   tanh(x) = 1 - 2/(2^(C2L*x) + 1),  2^(C2L*(e+d+b1)) = Ep * Dp
// Ep/Dp precomputed fp16 in the projection epilogue. In the hot loop:
//   p = min(Ep*Dp + 1, 126)            (cap: err <= 0.016 where tanh ~ 1)
//   pairwise: rq = rcph(p0*p1); 1/p0 = p1*rq; 1/p1 = p0*rq   (4 rcph per 8)
//   A = 1 - 2*r
//
// ws: W1T f16 [1024][1024] @0 (2MiB) | W2T f16 [128][1024] @2MiB (256KiB)
//     Ep f16 [2048][1024] @2.25MiB (4MiB) | Dp f16 [512][1024] @6.25MiB (1MiB)

typedef _Float16 f16x8 __attribute__((ext_vector_type(8)));
typedef _Float16 f16x2 __attribute__((ext_vector_type(2)));
typedef float    f32x4 __attribute__((ext_vector_type(4)));

#define C2L 2.8853900817779268f

__device__ __forceinline__ float fast_exp2(float x) { return __builtin_amdgcn_exp2f(x); }

// v_cvt_pkrtz_f16_f32 returns __fp16x2 — bitcast to our _Float16x2
__device__ __forceinline__ f16x2 pk_cvt(float x, float y) {
    auto r = __builtin_amdgcn_cvt_pkrtz(x, y);
    union { decltype(r) a; f16x2 b; } c; c.a = r; return c.b;
}

// tanh on 8 packed f16 via pairwise reciprocal (4 rcph instead of 8).
// p = e*d + 1 in (1, inf); capped at 126 so q = p0*p1 <= 15876 keeps
// rq = rcph(q) >= 6.3e-5 in the f16 normal range (no denormal/overflow path).
__device__ __forceinline__ f16x8 tanh8(f16x8 e, f16x8 d) {
    const f16x8 one = {1,1,1,1,1,1,1,1};
    const f16x8 two = {2,2,2,2,2,2,2,2};
    const f16x8 cap = {126,126,126,126,126,126,126,126};
    union { f16x8 v; _Float16 s[8]; } p, r;
    p.v = e * d + one;                              // v_pk_fma_f16 x4
    p.v = __builtin_elementwise_min(p.v, cap);      // v_pk_min_f16 x4
    #pragma unroll
    for (int i = 0; i < 4; ++i) {
        _Float16 q  = p.s[2*i] * p.s[2*i+1];
        _Float16 rq = __builtin_amdgcn_rcph(q);
        r.s[2*i]   = p.s[2*i+1] * rq;               // = 1/p0
        r.s[2*i+1] = p.s[2*i]   * rq;               // = 1/p1
    }
    return one - two * r.v;                         // v_pk_fma_f16 x4
}

// async 16B global -> LDS (LDS dest is wave-uniform base + lane*16)
__device__ __forceinline__ void stage16(const void* g, void* l) {
    __builtin_amdgcn_global_load_lds(
        (const __attribute__((address_space(1))) unsigned int*)g,
        (__attribute__((address_space(3))) unsigned int*)l, 16, 0, 0);
}

// ---------------------------------------------------------------- transpose
// bx<32: W1 (1024x1024) -> W1T ; bx>=32: W2 (1024x128) -> W2T
__global__ __launch_bounds__(1024) void transpose_both(
    const float* __restrict__ W1, const float* __restrict__ W2,
    _Float16* __restrict__ W1T, _Float16* __restrict__ W2T)
{
    __shared__ float tile[32][33];
    int bx = blockIdx.x;
    const float* src; _Float16* dst; int C, c0;
    if (bx < 32) { src = W1; dst = W1T; C = 1024; c0 = bx * 32; }
    else         { src = W2; dst = W2T; C = 128;  c0 = (bx - 32) * 32; }
    int r0 = blockIdx.y * 32;
    int tx = threadIdx.x, ty = threadIdx.y;
    tile[ty][tx] = src[(r0 + ty) * C + (c0 + tx)];
    __syncthreads();
    dst[(size_t)(c0 + ty) * 1024 + (r0 + tx)] = (_Float16)tile[tx][ty];
}

// ---------------------------------------------------------------- projections
// rows 0..2047 -> Ep = 2^(C2L*(enc@W1[:512] + b1)); rows 2048.. -> Dp (dec, no bias)
__global__ __launch_bounds__(256) void proj_exp(
    const float* __restrict__ enc,     // [2048][512]
    const float* __restrict__ dec,     // [512][512]
    const _Float16* __restrict__ W1T,  // [1024][1024]
    const float* __restrict__ b1,      // [1024]
    _Float16* __restrict__ Ep,         // [2048][1024]
    _Float16* __restrict__ Dp)         // [512][1024]
{
    const int K = 512;
    int tid  = threadIdx.x;
    int w    = tid >> 6, lane = tid & 63;
    int quad = lane >> 4, l15 = lane & 15;
    int m_base = blockIdx.y * 64 + w * 16;
    int n_base = blockIdx.x * 64;

    bool is_enc = (m_base < 2048);
    const float* A = is_enc ? (enc + (size_t)(m_base + l15) * K)
                            : (dec + (size_t)(m_base - 2048 + l15) * K);
    int koff = is_enc ? 0 : 512;

    f32x4 acc[4] = {};
    for (int kc = 0; kc < K; kc += 32) {
        int k = kc + quad * 8;
        float4 a_lo = *reinterpret_cast<const float4*>(A + k);
        float4 a_hi = *reinterpret_cast<const float4*>(A + k + 4);
        union { f16x8 v; f16x2 h[4]; } a;
        a.h[0] = pk_cvt(a_lo.x, a_lo.y);
        a.h[1] = pk_cvt(a_lo.z, a_lo.w);
        a.h[2] = pk_cvt(a_hi.x, a_hi.y);
        a.h[3] = pk_cvt(a_hi.z, a_hi.w);
        #pragma unroll
        for (int f = 0; f < 4; ++f) {
            int n = n_base + f * 16 + l15;
            f16x8 b = *reinterpret_cast<const f16x8*>(W1T + n * 1024 + koff + k);
            acc[f] = __builtin_amdgcn_mfma_f32_16x16x32_f16(a.v, b, acc[f], 0, 0, 0);
        }
    }

    #pragma unroll
    for (int f = 0; f < 4; ++f) {
        int col = n_base + f * 16 + l15;
        float bv = is_enc ? b1[col] : 0.0f;
        #pragma unroll
        for (int v = 0; v < 4; ++v) {
            int row = m_base + quad * 4 + v;
            float val = fast_exp2(C2L * (acc[f][v] + bv));
            if (is_enc) Ep[(size_t)row * 1024 + col] = (_Float16)val;
            else        Dp[(size_t)(row - 2048) * 1024 + col] = (_Float16)val;
        }
    }
}

// ---------------------------------------------------------------- main fused
// Block = (b, t-pair): 2 t x 64 u x 128 o. 4 waves; wave w owns u-rows
// [16w,16w+16) for both t. W2 staged in DOUBLE-BUFFERED LDS (BK=64, 2x16KiB):
// one barrier per tile; its vmcnt drain covers loads issued a full tile
// earlier, so the m97-style barrier-drain stall vanishes. XOR chunk swizzle
// keeps reads at 2-way bank aliasing (free) with the lane-linear LDS dest
// required by global_load_lds.
__global__ __launch_bounds__(256, 4) void joint_main(
    const _Float16* __restrict__ Ep,   // [2048][1024]
    const _Float16* __restrict__ Dp,   // [512][1024]
    const _Float16* __restrict__ W2T,  // [128][1024]
    const float* __restrict__ b2,      // [128]
    float* __restrict__ out)           // [8][256][64][128]
{
    __shared__ _Float16 sB[2][128 * 64];   // 2 x 16 KiB

    int t0 = blockIdx.x * 2, b = blockIdx.y;
    int tid  = threadIdx.x;
    int w    = tid >> 6, lane = tid & 63;
    int quad = lane >> 4, l15 = lane & 15;
    int u0   = w * 16;

    const _Float16* ep0 = Ep + (size_t)(b * 256 + t0) * 1024;
    const _Float16* ep1 = ep0 + 1024;
    const _Float16* dpr = Dp + (size_t)(b * 64 + u0 + l15) * 1024;

    f32x4 acc0[8] = {}, acc1[8] = {};

    // stage tile 0 into buf 0 (1024 chunks of 16B, 4 per thread)
    #pragma unroll
    for (int i = 0; i < 4; ++i) {
        int c = i * 256 + tid;
        int row = c >> 3, kcs = c & 7;
        stage16(W2T + row * 1024 + ((kcs ^ (row & 7)) << 3),
                &sB[0][(i * 256 + (tid & 0xC0)) * 8]);
    }

    for (int it = 0; it < 16; ++it) {
        __syncthreads();   // drains stage(it) — issued one full tile ago
        if (it < 15) {
            int kb = (it + 1) * 64;
            _Float16* dst = sB[(it + 1) & 1];
            #pragma unroll
            for (int i = 0; i < 4; ++i) {
                int c = i * 256 + tid;
                int row = c >> 3, kcs = c & 7;
                stage16(W2T + row * 1024 + kb + ((kcs ^ (row & 7)) << 3),
                        dst + (i * 256 + (tid & 0xC0)) * 8);
            }
        }
        const _Float16* sb = sB[it & 1];
        #pragma unroll
        for (int ki2 = 0; ki2 < 2; ++ki2) {
            int k = it * 64 + ki2 * 32 + quad * 8;
            f16x8 d8 = *reinterpret_cast<const f16x8*>(dpr + k);
            f16x8 e0 = *reinterpret_cast<const f16x8*>(ep0 + k);
            f16x8 e1 = *reinterpret_cast<const f16x8*>(ep1 + k);
            f16x8 A0 = tanh8(e0, d8);
            f16x8 A1 = tanh8(e1, d8);
            int kc3 = ki2 * 4 + quad;
            int sw  = (kc3 ^ (l15 & 7)) << 3;        // uniform across f
            #pragma unroll
            for (int f = 0; f < 8; ++f) {
                f16x8 bb = *reinterpret_cast<const f16x8*>(
                    sb + (f * 16 + l15) * 64 + sw);
                acc0[f] = __builtin_amdgcn_mfma_f32_16x16x32_f16(A0, bb, acc0[f], 0, 0, 0);
                acc1[f] = __builtin_amdgcn_mfma_f32_16x16x32_f16(A1, bb, acc1[f], 0, 0, 0);
            }
        }
    }

    float* o0 = out + (size_t)(b * 256 + t0) * 64 * 128;
    float* o1 = o0 + 64 * 128;
    #pragma unroll
    for (int f = 0; f < 8; ++f) {
        int o = f * 16 + l15;
        float bv = b2[o];
        #pragma unroll
        for (int v = 0; v < 4; ++v) {
            int u = u0 + quad * 4 + v;
            o0[u * 128 + o] = acc0[f][v] + bv;
            o1[u * 128 + o] = acc1[f][v] + bv;
        }
    }
}

// ---------------------------------------------------------------- launch
extern "C" void kernel_launch(void* const* d_in, const int* in_sizes, int n_in,
                              void* d_out, int out_size, void* d_ws, size_t ws_size,
                              hipStream_t stream) {
    const float* enc = (const float*)d_in[0]; // [8][256][512]
    const float* dec = (const float*)d_in[1]; // [8][64][512]
    const float* W1  = (const float*)d_in[2]; // [1024][1024]
    const float* b1  = (const float*)d_in[3]; // [1024]
    const float* W2  = (const float*)d_in[4]; // [1024][128]
    const float* b2  = (const float*)d_in[5]; // [128]
    float* out = (float*)d_out;

    char* ws = (char*)d_ws;
    _Float16* W1T = (_Float16*)(ws);                               // 2 MiB
    _Float16* W2T = (_Float16*)(ws + (2u << 20));                  // 256 KiB
    _Float16* EpP = (_Float16*)(ws + (2u << 20) + (256u << 10));   // 4 MiB
    _Float16* DpP = (_Float16*)(ws + (6u << 20) + (256u << 10));   // 1 MiB

    transpose_both<<<dim3(36, 32), dim3(32, 32), 0, stream>>>(W1, W2, W1T, W2T);

    // fused projections + exp2 epilogue: M = 2048 (enc) + 512 (dec)
    proj_exp<<<dim3(16, 40), 256, 0, stream>>>(enc, dec, W1T, b1, EpP, DpP);

    joint_main<<<dim3(128, 8), 256, 0, stream>>>(EpP, DpP, W2T, b2, out);
}